// Round 16
// baseline (193.626 us; speedup 1.0000x reference)
//
#include <hip/hip_runtime.h>
#include <math.h>

#define NPTS 8192
#define NB 2
#define CCH 128
#define KNN 16

typedef __attribute__((ext_vector_type(2))) float f32x2;

// ---------------- K-1: zero cnt (4KB region) + hist (32KB) -------
__global__ __launch_bounds__(256) void k_zero(float* __restrict__ p) {
  p[blockIdx.x * 256 + threadIdx.x] = 0.f;
}

// ---------------- spatial binning: 16^3 grid over [-4,4], morton order ------
__device__ __forceinline__ int spread4(int v) {
  return (v & 1) | ((v & 2) << 2) | ((v & 4) << 4) | ((v & 8) << 6);
}
__device__ __forceinline__ int cell_of(float x, float y, float z) {
  int cx = (int)fminf(fmaxf((x + 4.f) * 2.f, 0.f), 15.f);
  int cy = (int)fminf(fmaxf((y + 4.f) * 2.f, 0.f), 15.f);
  int cz = (int)fminf(fmaxf((z + 4.f) * 2.f, 0.f), 15.f);
  return spread4(cx) | (spread4(cy) << 1) | (spread4(cz) << 2);
}

__global__ __launch_bounds__(256) void k_hist(const float* __restrict__ pos,
                                              int* __restrict__ hist) {
  int i = blockIdx.x * 256 + threadIdx.x;   // 0..16383
  int b = i >> 13, n = i & 8191;
  const float* p = pos + (size_t)b * 3 * NPTS;
  int c = cell_of(p[n], p[NPTS + n], p[2 * NPTS + n]);
  atomicAdd(&hist[b * 4096 + c], 1);
}

// exclusive scan of 2 x 4096 bins (segmented at 512 threads), one block.
// Also zeroes the 1024-float stats block (stats1/stats2/s_sum/gate).
__global__ __launch_bounds__(1024) void k_scan(const int* __restrict__ hist,
                                               int* __restrict__ hoff,
                                               float* __restrict__ stats) {
  __shared__ int part[1024];
  int t = threadIdx.x;
  stats[t] = 0.f;
  int v[8];
  int s = 0;
#pragma unroll
  for (int i = 0; i < 8; ++i) { v[i] = hist[t * 8 + i]; s += v[i]; }
  part[t] = s;
  __syncthreads();
  for (int off = 1; off < 512; off <<= 1) {
    int add = ((t & 511) >= off) ? part[t - off] : 0;
    __syncthreads();
    part[t] += add;
    __syncthreads();
  }
  int ex = part[t] - s;
#pragma unroll
  for (int i = 0; i < 8; ++i) { hoff[t * 8 + i] = ex; ex += v[i]; }
}

// scatter: sorted positions (x,y,z,|p|^2) + rank of each original point
__global__ __launch_bounds__(256) void k_scatter(const float* __restrict__ pos,
                                                 int* __restrict__ hoff,
                                                 float4* __restrict__ spos,
                                                 int* __restrict__ rank) {
  int i = blockIdx.x * 256 + threadIdx.x;
  int b = i >> 13, n = i & 8191;
  const float* p = pos + (size_t)b * 3 * NPTS;
  float x = p[n], y = p[NPTS + n], z = p[2 * NPTS + n];
  int c = cell_of(x, y, z);
  int slot = atomicAdd(&hoff[b * 4096 + c], 1);
  spos[(b << 13) + slot] = make_float4(x, y, z, fmaf(x, x, fmaf(y, y, z * z)));
  rank[(b << 13) + n] = slot;
}

// ---------------- K0: transpose x [B,C,N] -> xT [B,N,C] ----------------
__global__ __launch_bounds__(256) void k_transpose(const float* __restrict__ x,
                                                   float* __restrict__ xT) {
  __shared__ float t[32][65];
  int blk = blockIdx.x;
  int b = blk >> 9;
  int rem = blk & 511;
  int c0 = (rem >> 7) << 5;
  int n0 = (rem & 127) << 6;
  const float* xb = x + (size_t)b * CCH * NPTS;
  float* xTb = xT + (size_t)b * NPTS * CCH;
  int nj = threadIdx.x & 63, ci = threadIdx.x >> 6;
#pragma unroll
  for (int i = 0; i < 8; ++i) {
    int c = ci * 8 + i;
    t[c][nj] = xb[(size_t)(c0 + c) * NPTS + n0 + nj];
  }
  __syncthreads();
  int cl = threadIdx.x & 31, nl = threadIdx.x >> 5;
#pragma unroll
  for (int i = 0; i < 8; ++i) {
    int n = nl * 8 + i;
    xTb[(size_t)(n0 + n) * CCH + c0 + cl] = t[cl][n];
  }
}

// ---------------- K1: KNN (R12 exact): brute scan, 64-window seed -----------
#define SWZF(v, imm) __int_as_float(__builtin_amdgcn_ds_swizzle(__float_as_int(v), (imm)))
#define RDLANEF(v, l) __int_as_float(__builtin_amdgcn_readlane(__float_as_int(v), (l)))
#define DPPF(x) __int_as_float(__builtin_amdgcn_mov_dpp(__float_as_int(x), 0x111, 0xf, 0xf, true))
#define DPPI(x) __builtin_amdgcn_mov_dpp((x), 0x111, 0xf, 0xf, true)

#define BST(var, K, J, IMM)                                        \
  {                                                                \
    float od = SWZF(var, IMM);                                     \
    bool up = ((sub & (K)) == 0);                                  \
    bool low = ((sub & (J)) == 0);                                 \
    bool take = low ? ((var > od) == up) : ((var < od) == up);     \
    if (take) var = od;                                            \
  }
#define BSORT32(v)                                                  \
  BST(v, 2, 1, 0x041F)                                              \
  BST(v, 4, 2, 0x081F)  BST(v, 4, 1, 0x041F)                        \
  BST(v, 8, 4, 0x101F)  BST(v, 8, 2, 0x081F)  BST(v, 8, 1, 0x041F)  \
  BST(v, 16, 8, 0x201F) BST(v, 16, 4, 0x101F) BST(v, 16, 2, 0x081F) \
  BST(v, 16, 1, 0x041F)                                             \
  BST(v, 32, 16, 0x401F) BST(v, 32, 8, 0x201F) BST(v, 32, 4, 0x101F)\
  BST(v, 32, 2, 0x081F) BST(v, 32, 1, 0x041F)
#define BCLEAN32(v)                                                 \
  BST(v, 32, 16, 0x401F) BST(v, 32, 8, 0x201F) BST(v, 32, 4, 0x101F)\
  BST(v, 32, 2, 0x081F) BST(v, 32, 1, 0x041F)

__global__ __launch_bounds__(512, 8) void k_knn(const float* __restrict__ pos,
                                                const float4* __restrict__ spos,
                                                const int* __restrict__ rank,
                                                int* __restrict__ nn_idx,
                                                float* __restrict__ nn_w) {
  __shared__ float4 cpos[2048];                   // 32 KB chunk (x,y,z,|p|^2)
  const int b = blockIdx.x >> 9;                  // 512 blocks per batch
  const int wid = threadIdx.x >> 6;
  const int lane = threadIdx.x & 63;
  const int sub = lane & 31;
  const int grp = lane >> 5;
  const int base = b << 13;
  const int qbase = ((blockIdx.x & 511) << 4) + (wid << 1);
  const int q = qbase + grp;                      // own query (original index)
  const float* px = pos + (size_t)b * 3 * NPTS;
  const float* py = px + NPTS;
  const float* pz = py + NPTS;
  const float qAx = px[qbase], qAy = py[qbase], qAz = pz[qbase];
  const float qBx = px[qbase + 1], qBy = py[qbase + 1], qBz = pz[qbase + 1];
  const float n2Ax = -2.f * qAx, n2Ay = -2.f * qAy, n2Az = -2.f * qAz;
  const float n2Bx = -2.f * qBx, n2By = -2.f * qBy, n2Bz = -2.f * qBz;
  const float qAsq = fmaf(qAx, qAx, fmaf(qAy, qAy, qAz * qAz));
  const float qBsq = fmaf(qBx, qBx, fmaf(qBy, qBy, qBz * qBz));
  const float nsx = grp ? n2Bx : n2Ax;            // self-query consts (seed)
  const float nsy = grp ? n2By : n2Ay;
  const float nsz = grp ? n2Bz : n2Az;
  const float sqs = grp ? qBsq : qAsq;
  const float qsx = grp ? qBx : qAx;
  const float qsy = grp ? qBy : qAy;
  const float qsz = grp ? qBz : qAz;
  const bool holder = (sub < 16);

  // ---- seed: Tv0 = exact 16th-smallest d2 of the 64-slot sorted window ----
  float Tv0A, Tv0B;
  {
    int rk = rank[base + q];                      // uniform within each half
    int seedW = rk & ~63;
    float4 c0 = spos[base + seedW + sub];
    float4 c1 = spos[base + seedW + 32 + sub];
    float sd = fmaf(c0.z, nsz, fmaf(c0.y, nsy, fmaf(c0.x, nsx, c0.w + sqs)));
    float se = fmaf(c1.z, nsz, fmaf(c1.y, nsy, fmaf(c1.x, nsx, c1.w + sqs)));
    BSORT32(sd)
    BSORT32(se)
    float ser = SWZF(se, 0x7C1F);                 // reverse within 32 lanes
    sd = fminf(sd, ser);                          // bitonic lower-32 of union
    BCLEAN32(sd)
    Tv0A = RDLANEF(sd, 15);
    Tv0B = RDLANEF(sd, 47);
  }
  float TvA = Tv0A, TvB = Tv0B;
  float bd = 3.4e38f;                             // holders: sorted top-16 d2
  int bi = 0;                                     // original candidate index

  for (int ch = 0; ch < 4; ++ch) {
    __syncthreads();
    for (int i = threadIdx.x; i < 2048; i += 512) {
      int j = (ch << 11) + i;
      float x = px[j], y = py[j], z = pz[j];
      cpos[i] = make_float4(x, y, z, fmaf(x, x, fmaf(y, y, z * z)));
    }
    __syncthreads();
    for (int t = 0; t < 32; ++t) {
      float4 cp = cpos[(t << 6) + lane];
      float d2A = fmaf(cp.z, n2Az, fmaf(cp.y, n2Ay, fmaf(cp.x, n2Ax, cp.w + qAsq)));
      float d2B = fmaf(cp.z, n2Bz, fmaf(cp.y, n2By, fmaf(cp.x, n2Bx, cp.w + qBsq)));
      unsigned long long mA = __ballot(d2A <= TvA);
      unsigned long long mB = __ballot(d2B <= TvB);
      if (mA | mB) {
        const int cb = (ch << 11) + (t << 6);
        while (mA) {
          int l = __builtin_ctzll(mA);
          mA &= mA - 1;
          float v = RDLANEF(d2A, l);
          if (v > TvA) continue;                  // stale vs tightened T
          int vi = cb + l;
          float ud = DPPF(bd);                    // prev-lane value (in-row)
          int ui = DPPI(bi);
          bool gt = (lane < 16) && (bd > v);
          bool first = (sub == 0) || (ud <= v);
          if (gt) {
            bd = first ? v : ud;
            bi = first ? vi : ui;
          }
          TvA = fminf(Tv0A, RDLANEF(bd, 15));
        }
        while (mB) {
          int l = __builtin_ctzll(mB);
          mB &= mB - 1;
          float v = RDLANEF(d2B, l);
          if (v > TvB) continue;
          int vi = cb + l;
          float ud = DPPF(bd);
          int ui = DPPI(bi);
          bool gt = (lane >= 32) && (lane < 48) && (bd > v);
          bool first = (sub == 0) || (ud <= v);
          if (gt) {
            bd = first ? v : ud;
            bi = first ? vi : ui;
          }
          TvB = fminf(Tv0B, RDLANEF(bd, 47));
        }
      }
    }
  }

  // exact-diff distance (matches reference) + softmax over each 16
  float dx = qsx - px[bi], dy = qsy - py[bi], dz = qsz - pz[bi];
  float dd = fmaxf(sqrtf(fmaf(dx, dx, fmaf(dy, dy, dz * dz))), 1e-6f);
  float logit = -dd * 5.0f;                       // 1/TAU = 5
  float mx = holder ? logit : -3.4e38f;
  mx = fmaxf(mx, SWZF(mx, 0x041F));
  mx = fmaxf(mx, SWZF(mx, 0x081F));
  mx = fmaxf(mx, SWZF(mx, 0x101F));
  mx = fmaxf(mx, SWZF(mx, 0x201F));
  float e = holder ? __expf(logit - mx) : 0.f;
  float s = e;
  s += SWZF(s, 0x041F);
  s += SWZF(s, 0x081F);
  s += SWZF(s, 0x101F);
  s += SWZF(s, 0x201F);
  if (holder) {
    size_t o = ((size_t)b * NPTS + q) * KNN + sub;
    nn_idx[o] = bi;
    nn_w[o] = e / s;
  }
}

// ------- K2: FUSED agg + GEMM1: h = [xT | agg][32x256] x w1^T + BN1 stats ---
// 8 K-chunks of 32 cols (LDS 41KB -> 3 blocks/CU for gather latency hiding).
// Packed f32x2 accumulation -> v_pk_fma_f32. Column order identical to the
// 64-col version -> bitwise-identical results.
#define GEMM_CHUNK8(ASRC)                                                    \
    _Pragma("unroll")                                                        \
    for (int cq = 0; cq < 8; ++cq) {                                         \
      int c = cq << 2;                                                       \
      float4 a[4], w[4];                                                     \
      _Pragma("unroll")                                                      \
      for (int i = 0; i < 4; ++i) a[i] = ASRC;                               \
      _Pragma("unroll")                                                      \
      for (int j = 0; j < 4; ++j) w[j] = *(const float4*)&wlds[og + (j << 5)][c]; \
      _Pragma("unroll")                                                      \
      for (int i = 0; i < 4; ++i) {                                          \
        f32x2 a01 = {a[i].x, a[i].y}, a23 = {a[i].z, a[i].w};                \
        _Pragma("unroll")                                                    \
        for (int j = 0; j < 4; ++j) {                                        \
          f32x2 w01 = {w[j].x, w[j].y}, w23 = {w[j].z, w[j].w};              \
          acc2[i][j] += a01 * w01;                                           \
          acc2[i][j] += a23 * w23;                                           \
        }                                                                    \
      }                                                                      \
    }

__global__ __launch_bounds__(256) void k_gemm1(const float* __restrict__ xT,
                                               const int* __restrict__ nn_idx,
                                               const float* __restrict__ nn_w,
                                               const float* __restrict__ w1,
                                               float* __restrict__ h_pre,
                                               float* __restrict__ stats1) {
  __shared__ float alds[32][36];
  __shared__ float wlds[128][36];
  __shared__ float aggl[32][132];
  __shared__ float sred[256];
  int b = blockIdx.x >> 8;
  int r0 = (blockIdx.x & 255) << 5;
  const float* xTb = xT + (size_t)b * NPTS * CCH;
  int rg = threadIdx.x & 7, og = threadIdx.x >> 3;
  f32x2 acc2[4][4];
#pragma unroll
  for (int i = 0; i < 4; ++i)
#pragma unroll
    for (int j = 0; j < 4; ++j) acc2[i][j] = (f32x2){0.f, 0.f};
  sred[threadIdx.x] = 0.f;

  {  // aggregation prologue: thread = (row r = tid>>3, 16-ch group cg = tid&7)
    int r = threadIdx.x >> 3, cg = threadIdx.x & 7;
    size_t o = ((size_t)b * NPTS + r0 + r) * KNN;
    float ag[16];
#pragma unroll
    for (int i = 0; i < 16; ++i) ag[i] = 0.f;
    for (int k = 0; k < KNN; ++k) {
      int idx = nn_idx[o + k];
      float w = nn_w[o + k];
      const float4* src = (const float4*)(xTb + (size_t)idx * CCH + (cg << 4));
#pragma unroll
      for (int u = 0; u < 4; ++u) {
        float4 v = src[u];
        ag[u * 4 + 0] = fmaf(w, v.x, ag[u * 4 + 0]);
        ag[u * 4 + 1] = fmaf(w, v.y, ag[u * 4 + 1]);
        ag[u * 4 + 2] = fmaf(w, v.z, ag[u * 4 + 2]);
        ag[u * 4 + 3] = fmaf(w, v.w, ag[u * 4 + 3]);
      }
    }
#pragma unroll
    for (int u = 0; u < 4; ++u)
      *(float4*)&aggl[r][(cg << 4) + (u << 2)] =
          make_float4(ag[u * 4], ag[u * 4 + 1], ag[u * 4 + 2], ag[u * 4 + 3]);
  }

  for (int ch = 0; ch < 8; ++ch) {
    __syncthreads();   // ch=0 barrier also publishes aggl for ch>=4 reads
    if (ch < 4) {      // stage A (xT half): 32 x 32, 1 float4/thread
      int r = threadIdx.x >> 3, kq = threadIdx.x & 7;
      *(float4*)&alds[r][kq << 2] =
          *(const float4*)(xTb + (size_t)(r0 + r) * CCH + (ch << 5) + (kq << 2));
    }
#pragma unroll
    for (int it = 0; it < 4; ++it) {              // stage W: 128 x 32
      int i = threadIdx.x + it * 256;
      int h = i >> 3, kq = i & 7;
      *(float4*)&wlds[h][kq << 2] =
          *(const float4*)(w1 + (size_t)h * 256 + (ch << 5) + (kq << 2));
    }
    __syncthreads();
    if (ch < 4) {
      GEMM_CHUNK8(*(const float4*)&alds[rg + (i << 3)][c])
    } else {
      GEMM_CHUNK8(*(const float4*)&aggl[rg + (i << 3)][((ch - 4) << 5) + c])
    }
  }
  float acc[4][4];
#pragma unroll
  for (int i = 0; i < 4; ++i)
#pragma unroll
    for (int j = 0; j < 4; ++j) acc[i][j] = acc2[i][j].x + acc2[i][j].y;
#pragma unroll
  for (int i = 0; i < 4; ++i) {
    int row = r0 + rg + (i << 3);
    float* dst = h_pre + ((size_t)b * NPTS + row) * CCH;
#pragma unroll
    for (int j = 0; j < 4; ++j) dst[og + (j << 5)] = acc[i][j];
  }
#pragma unroll
  for (int j = 0; j < 4; ++j) {
    float ps = acc[0][j] + acc[1][j] + acc[2][j] + acc[3][j];
    float pq = acc[0][j] * acc[0][j] + acc[1][j] * acc[1][j] +
               acc[2][j] * acc[2][j] + acc[3][j] * acc[3][j];
    atomicAdd(&sred[og + (j << 5)], ps);
    atomicAdd(&sred[128 + og + (j << 5)], pq);
  }
  __syncthreads();
  atomicAdd(&stats1[threadIdx.x], sred[threadIdx.x]);
}

// ---------------- K4: BN1+ReLU + GEMM2 + BN2 stats (4 chunks of 32) ---------
__global__ __launch_bounds__(256) void k_gemm2(const float* __restrict__ h_pre,
                                               const float* __restrict__ stats1,
                                               const float* __restrict__ g1,
                                               const float* __restrict__ b1,
                                               const float* __restrict__ w2,
                                               float* __restrict__ y_pre,
                                               float* __restrict__ stats2) {
  __shared__ float alds[32][36];
  __shared__ float wlds[128][36];
  __shared__ float sred[256];
  __shared__ float scs[128], shs[128];
  int b = blockIdx.x >> 8;
  int r0 = (blockIdx.x & 255) << 5;
  int rg = threadIdx.x & 7, og = threadIdx.x >> 3;
  f32x2 acc2[4][4];
#pragma unroll
  for (int i = 0; i < 4; ++i)
#pragma unroll
    for (int j = 0; j < 4; ++j) acc2[i][j] = (f32x2){0.f, 0.f};
  sred[threadIdx.x] = 0.f;
  if (threadIdx.x < 128) {
    int c = threadIdx.x;
    float sm = stats1[c] * (1.f / 16384.f);
    float sq = stats1[128 + c] * (1.f / 16384.f);
    float var = fmaxf(sq - sm * sm, 0.f);
    float sc = g1[c] * rsqrtf(var + 1e-5f);
    scs[c] = sc;
    shs[c] = b1[c] - sm * sc;
  }
  for (int ch = 0; ch < 4; ++ch) {
    __syncthreads();
    {  // stage A = relu(bn1(h_pre)) 32 x 32, 1 float4/thread
      int r = threadIdx.x >> 3, kq = threadIdx.x & 7;
      int c = (ch << 5) + (kq << 2);
      float4 v = *(const float4*)(h_pre + ((size_t)b * NPTS + r0 + r) * CCH + c);
      float4 sc = *(const float4*)&scs[c];
      float4 sh = *(const float4*)&shs[c];
      v.x = fmaxf(fmaf(v.x, sc.x, sh.x), 0.f);
      v.y = fmaxf(fmaf(v.y, sc.y, sh.y), 0.f);
      v.z = fmaxf(fmaf(v.z, sc.z, sh.z), 0.f);
      v.w = fmaxf(fmaf(v.w, sc.w, sh.w), 0.f);
      *(float4*)&alds[r][kq << 2] = v;
    }
#pragma unroll
    for (int it = 0; it < 4; ++it) {              // stage W2: 128 x 32
      int i = threadIdx.x + it * 256;
      int h = i >> 3, kq = i & 7;
      *(float4*)&wlds[h][kq << 2] =
          *(const float4*)(w2 + (size_t)h * CCH + (ch << 5) + (kq << 2));
    }
    __syncthreads();
#pragma unroll
    for (int cq = 0; cq < 8; ++cq) {
      int c = cq << 2;
      float4 a[4], w[4];
#pragma unroll
      for (int i = 0; i < 4; ++i) a[i] = *(const float4*)&alds[rg + (i << 3)][c];
#pragma unroll
      for (int j = 0; j < 4; ++j) w[j] = *(const float4*)&wlds[og + (j << 5)][c];
#pragma unroll
      for (int i = 0; i < 4; ++i) {
        f32x2 a01 = {a[i].x, a[i].y}, a23 = {a[i].z, a[i].w};
#pragma unroll
        for (int j = 0; j < 4; ++j) {
          f32x2 w01 = {w[j].x, w[j].y}, w23 = {w[j].z, w[j].w};
          acc2[i][j] += a01 * w01;
          acc2[i][j] += a23 * w23;
        }
      }
    }
  }
  float acc[4][4];
#pragma unroll
  for (int i = 0; i < 4; ++i)
#pragma unroll
    for (int j = 0; j < 4; ++j) acc[i][j] = acc2[i][j].x + acc2[i][j].y;
#pragma unroll
  for (int i = 0; i < 4; ++i) {
    int row = r0 + rg + (i << 3);
    float* dst = y_pre + ((size_t)b * NPTS + row) * CCH;
#pragma unroll
    for (int j = 0; j < 4; ++j) dst[og + (j << 5)] = acc[i][j];
  }
#pragma unroll
  for (int j = 0; j < 4; ++j) {
    float ps = acc[0][j] + acc[1][j] + acc[2][j] + acc[3][j];
    float pq = acc[0][j] * acc[0][j] + acc[1][j] * acc[1][j] +
               acc[2][j] * acc[2][j] + acc[3][j] * acc[3][j];
    atomicAdd(&sred[og + (j << 5)], ps);
    atomicAdd(&sred[128 + og + (j << 5)], pq);
  }
  __syncthreads();
  atomicAdd(&stats2[threadIdx.x], sred[threadIdx.x]);
}

// ------- K6: SE pool + (last block) SE gate — fused via device counter ------
__global__ __launch_bounds__(256) void k_sepool(const float* __restrict__ y_pre,
                                                const float* __restrict__ stats2,
                                                const float* __restrict__ g2,
                                                const float* __restrict__ b2,
                                                const float* __restrict__ fc1w,
                                                const float* __restrict__ fc1b,
                                                const float* __restrict__ fc2w,
                                                const float* __restrict__ fc2b,
                                                float* __restrict__ s_sum,
                                                float* __restrict__ gate,
                                                int* __restrict__ cnt) {
  __shared__ float red[256];
  __shared__ float hid2[16];
  __shared__ int last;
  int b = blockIdx.x >> 7;
  int r0 = (blockIdx.x & 127) << 6;
  int c = threadIdx.x & 127, half = threadIdx.x >> 7;
  float sm = stats2[c] * (1.f / 16384.f);
  float sq = stats2[128 + c] * (1.f / 16384.f);
  float var = fmaxf(sq - sm * sm, 0.f);
  float sc = g2[c] * rsqrtf(var + 1e-5f);
  float sh = b2[c] - sm * sc;
  float acc = 0.f;
  for (int r = half; r < 64; r += 2) {
    float v = y_pre[((size_t)b * NPTS + r0 + r) * CCH + c];
    acc += fmaxf(v * sc + sh, 0.f);
  }
  red[threadIdx.x] = acc;
  __syncthreads();
  if (half == 0) atomicAdd(&s_sum[b * CCH + c], red[c] + red[128 + c]);
  __threadfence();
  __syncthreads();
  if (threadIdx.x == 0) last = (atomicAdd(cnt, 1) == 255);
  __syncthreads();
  if (last) {                                    // uniform branch
    __threadfence();
    int t = threadIdx.x;
    red[t] = s_sum[(t >> 7) * CCH + (t & 127)] * (1.f / 8192.f);
    __syncthreads();
    if (t < 16) {
      int bb = t >> 3, j = t & 7;
      float a = fc1b[j];
      for (int cc = 0; cc < 128; ++cc) a += red[bb * 128 + cc] * fc1w[j * 128 + cc];
      hid2[t] = fmaxf(a, 0.f);
    }
    __syncthreads();
    float a = fc2b[t & 127];
#pragma unroll
    for (int j = 0; j < 8; ++j) a += hid2[(t >> 7) * 8 + j] * fc2w[(t & 127) * 8 + j];
    gate[(t >> 7) * CCH + (t & 127)] = 1.f / (1.f + __expf(-a));
  }
}

// ---------------- K8: bn2+relu+gate + residual + transpose ----------------
__global__ __launch_bounds__(256) void k_out(const float* __restrict__ x,
                                             const float* __restrict__ y_pre,
                                             const float* __restrict__ stats2,
                                             const float* __restrict__ g2,
                                             const float* __restrict__ b2,
                                             const float* __restrict__ gate,
                                             float* __restrict__ out) {
  __shared__ float t[64][129];
  int b = blockIdx.x >> 7;
  int n0 = (blockIdx.x & 127) << 6;
  {
    int c = threadIdx.x & 127;
    float sm = stats2[c] * (1.f / 16384.f);
    float sq = stats2[128 + c] * (1.f / 16384.f);
    float var = fmaxf(sq - sm * sm, 0.f);
    float sc = g2[c] * rsqrtf(var + 1e-5f);
    float sh = b2[c] - sm * sc;
    float gt = gate[b * CCH + c];
    for (int r = threadIdx.x >> 7; r < 64; r += 2) {
      float v = y_pre[((size_t)b * NPTS + n0 + r) * CCH + c];
      t[r][c] = fmaxf(v * sc + sh, 0.f) * gt;
    }
  }
  __syncthreads();
  int nl = threadIdx.x & 63, cg = threadIdx.x >> 6;
  for (int cc = cg; cc < CCH; cc += 4) {
    size_t o = ((size_t)b * CCH + cc) * NPTS + n0 + nl;
    out[o] = x[o] + t[nl][cc];
  }
}

extern "C" void kernel_launch(void* const* d_in, const int* in_sizes, int n_in,
                              void* d_out, int out_size, void* d_ws, size_t ws_size,
                              hipStream_t stream) {
  const float* x = (const float*)d_in[0];
  const float* pos = (const float*)d_in[1];
  const float* w1 = (const float*)d_in[2];
  const float* g1 = (const float*)d_in[3];
  const float* b1 = (const float*)d_in[4];
  const float* w2 = (const float*)d_in[5];
  const float* g2 = (const float*)d_in[6];
  const float* b2 = (const float*)d_in[7];
  const float* fc1w = (const float*)d_in[8];
  const float* fc1b = (const float*)d_in[9];
  const float* fc2w = (const float*)d_in[10];
  const float* fc2b = (const float*)d_in[11];
  float* out = (float*)d_out;
  char* ws = (char*)d_ws;
  const size_t MB = 1048576;

  float* xT = (float*)(ws + 0);             //  8 MB [B,N,128]
  int* nn_idx = (int*)(ws + 8 * MB);        //  1 MB
  float* nn_w = (float*)(ws + 9 * MB);      //  1 MB
  float* h_pre = (float*)(ws + 18 * MB);    //  8 MB
  // meta at 26MB: [stats 4KB (zeroed by k_scan)][cnt 4KB (zeroed by k_zero)]
  //               [hist 32KB (zeroed by k_zero)][hoff 32KB][spos 256KB][rank 64KB]
  char* meta = ws + 26 * MB;
  float* stats = (float*)meta;
  int* cnt = (int*)(meta + 4096);
  int* hist = (int*)(meta + 8192);
  int* hoff = (int*)(meta + 8192 + 32768);
  float4* spos = (float4*)(meta + 8192 + 65536);
  int* rank = (int*)(meta + 8192 + 65536 + 262144);
  float* y_pre;
  if (ws_size >= 35 * MB) {
    y_pre = (float*)(ws + 27 * MB);         //  8 MB disjoint
  } else {
    y_pre = (float*)(ws + 0);               //  aliases xT (dead after k_gemm1,
  }                                         //  rewritten first thing next call)
  float* stats1 = stats;
  float* stats2 = stats + 256;
  float* s_sum = stats + 512;
  float* gate = stats + 768;

  k_zero<<<36, 256, 0, stream>>>((float*)(meta + 4096));  // cnt region + hist
  k_hist<<<64, 256, 0, stream>>>(pos, hist);
  k_scan<<<1, 1024, 0, stream>>>(hist, hoff, stats);
  k_scatter<<<64, 256, 0, stream>>>(pos, hoff, spos, rank);
  k_transpose<<<1024, 256, 0, stream>>>(x, xT);
  k_knn<<<1024, 512, 0, stream>>>(pos, spos, rank, nn_idx, nn_w);
  k_gemm1<<<512, 256, 0, stream>>>(xT, nn_idx, nn_w, w1, h_pre, stats1);
  k_gemm2<<<512, 256, 0, stream>>>(h_pre, stats1, g1, b1, w2, y_pre, stats2);
  k_sepool<<<256, 256, 0, stream>>>(y_pre, stats2, g2, b2, fc1w, fc1b, fc2w,
                                    fc2b, s_sum, gate, cnt);
  k_out<<<256, 256, 0, stream>>>(x, y_pre, stats2, g2, b2, gate, out);
}

// Round 17
// 171.340 us; speedup vs baseline: 1.1301x; 1.1301x over previous
//
#include <hip/hip_runtime.h>
#include <math.h>

#define NPTS 8192
#define NB 2
#define CCH 128
#define KNN 16

typedef __attribute__((ext_vector_type(2))) float f32x2;

// ---------------- K-1: zero meta block (stats 4KB + hist 32KB) -------
__global__ __launch_bounds__(256) void k_zero(float* __restrict__ p) {
  p[blockIdx.x * 256 + threadIdx.x] = 0.f;
}

// ---------------- spatial binning: 16^3 grid over [-4,4], morton order ------
__device__ __forceinline__ int spread4(int v) {
  return (v & 1) | ((v & 2) << 2) | ((v & 4) << 4) | ((v & 8) << 6);
}
__device__ __forceinline__ int cell_of(float x, float y, float z) {
  int cx = (int)fminf(fmaxf((x + 4.f) * 2.f, 0.f), 15.f);
  int cy = (int)fminf(fmaxf((y + 4.f) * 2.f, 0.f), 15.f);
  int cz = (int)fminf(fmaxf((z + 4.f) * 2.f, 0.f), 15.f);
  return spread4(cx) | (spread4(cy) << 1) | (spread4(cz) << 2);
}

__global__ __launch_bounds__(256) void k_hist(const float* __restrict__ pos,
                                              int* __restrict__ hist) {
  int i = blockIdx.x * 256 + threadIdx.x;   // 0..16383
  int b = i >> 13, n = i & 8191;
  const float* p = pos + (size_t)b * 3 * NPTS;
  int c = cell_of(p[n], p[NPTS + n], p[2 * NPTS + n]);
  atomicAdd(&hist[b * 4096 + c], 1);
}

// exclusive scan of 2 x 4096 bins (segmented at 512 threads), one block
__global__ __launch_bounds__(1024) void k_scan(const int* __restrict__ hist,
                                               int* __restrict__ hoff) {
  __shared__ int part[1024];
  int t = threadIdx.x;
  int v[8];
  int s = 0;
#pragma unroll
  for (int i = 0; i < 8; ++i) { v[i] = hist[t * 8 + i]; s += v[i]; }
  part[t] = s;
  __syncthreads();
  for (int off = 1; off < 512; off <<= 1) {
    int add = ((t & 511) >= off) ? part[t - off] : 0;
    __syncthreads();
    part[t] += add;
    __syncthreads();
  }
  int ex = part[t] - s;
#pragma unroll
  for (int i = 0; i < 8; ++i) { hoff[t * 8 + i] = ex; ex += v[i]; }
}

// scatter: sorted positions (x,y,z,|p|^2) + rank of each original point
__global__ __launch_bounds__(256) void k_scatter(const float* __restrict__ pos,
                                                 int* __restrict__ hoff,
                                                 float4* __restrict__ spos,
                                                 int* __restrict__ rank) {
  int i = blockIdx.x * 256 + threadIdx.x;
  int b = i >> 13, n = i & 8191;
  const float* p = pos + (size_t)b * 3 * NPTS;
  float x = p[n], y = p[NPTS + n], z = p[2 * NPTS + n];
  int c = cell_of(x, y, z);
  int slot = atomicAdd(&hoff[b * 4096 + c], 1);
  spos[(b << 13) + slot] = make_float4(x, y, z, fmaf(x, x, fmaf(y, y, z * z)));
  rank[(b << 13) + n] = slot;
}

// ---------------- K0: transpose x [B,C,N] -> xT [B,N,C] ----------------
__global__ __launch_bounds__(256) void k_transpose(const float* __restrict__ x,
                                                   float* __restrict__ xT) {
  __shared__ float t[32][65];
  int blk = blockIdx.x;
  int b = blk >> 9;
  int rem = blk & 511;
  int c0 = (rem >> 7) << 5;
  int n0 = (rem & 127) << 6;
  const float* xb = x + (size_t)b * CCH * NPTS;
  float* xTb = xT + (size_t)b * NPTS * CCH;
  int nj = threadIdx.x & 63, ci = threadIdx.x >> 6;
#pragma unroll
  for (int i = 0; i < 8; ++i) {
    int c = ci * 8 + i;
    t[c][nj] = xb[(size_t)(c0 + c) * NPTS + n0 + nj];
  }
  __syncthreads();
  int cl = threadIdx.x & 31, nl = threadIdx.x >> 5;
#pragma unroll
  for (int i = 0; i < 8; ++i) {
    int n = nl * 8 + i;
    xTb[(size_t)(n0 + n) * CCH + c0 + cl] = t[cl][n];
  }
}

// ---------------- K1: KNN (R12 exact): brute scan, 64-window seed -----------
// Wave = 2 ORIGINAL-order queries (spatially random -> uniform block work).
// 4 x 32KB LDS chunks, 64 unique candidates/iter. Seed = exact 16th of the
// 64-slot morton window around rank[q]. LDS-free serial drains: readlane
// broadcast + DPP row_shr:1 shift-insert, per-event stale-skip + Tv refresh.

#define SWZF(v, imm) __int_as_float(__builtin_amdgcn_ds_swizzle(__float_as_int(v), (imm)))
#define RDLANEF(v, l) __int_as_float(__builtin_amdgcn_readlane(__float_as_int(v), (l)))
#define DPPF(x) __int_as_float(__builtin_amdgcn_mov_dpp(__float_as_int(x), 0x111, 0xf, 0xf, true))
#define DPPI(x) __builtin_amdgcn_mov_dpp((x), 0x111, 0xf, 0xf, true)

#define BST(var, K, J, IMM)                                        \
  {                                                                \
    float od = SWZF(var, IMM);                                     \
    bool up = ((sub & (K)) == 0);                                  \
    bool low = ((sub & (J)) == 0);                                 \
    bool take = low ? ((var > od) == up) : ((var < od) == up);     \
    if (take) var = od;                                            \
  }
#define BSORT32(v)                                                  \
  BST(v, 2, 1, 0x041F)                                              \
  BST(v, 4, 2, 0x081F)  BST(v, 4, 1, 0x041F)                        \
  BST(v, 8, 4, 0x101F)  BST(v, 8, 2, 0x081F)  BST(v, 8, 1, 0x041F)  \
  BST(v, 16, 8, 0x201F) BST(v, 16, 4, 0x101F) BST(v, 16, 2, 0x081F) \
  BST(v, 16, 1, 0x041F)                                             \
  BST(v, 32, 16, 0x401F) BST(v, 32, 8, 0x201F) BST(v, 32, 4, 0x101F)\
  BST(v, 32, 2, 0x081F) BST(v, 32, 1, 0x041F)
#define BCLEAN32(v)                                                 \
  BST(v, 32, 16, 0x401F) BST(v, 32, 8, 0x201F) BST(v, 32, 4, 0x101F)\
  BST(v, 32, 2, 0x081F) BST(v, 32, 1, 0x041F)

__global__ __launch_bounds__(512, 8) void k_knn(const float* __restrict__ pos,
                                                const float4* __restrict__ spos,
                                                const int* __restrict__ rank,
                                                int* __restrict__ nn_idx,
                                                float* __restrict__ nn_w) {
  __shared__ float4 cpos[2048];                   // 32 KB chunk (x,y,z,|p|^2)
  const int b = blockIdx.x >> 9;                  // 512 blocks per batch
  const int wid = threadIdx.x >> 6;
  const int lane = threadIdx.x & 63;
  const int sub = lane & 31;
  const int grp = lane >> 5;
  const int base = b << 13;
  const int qbase = ((blockIdx.x & 511) << 4) + (wid << 1);
  const int q = qbase + grp;                      // own query (original index)
  const float* px = pos + (size_t)b * 3 * NPTS;
  const float* py = px + NPTS;
  const float* pz = py + NPTS;
  const float qAx = px[qbase], qAy = py[qbase], qAz = pz[qbase];
  const float qBx = px[qbase + 1], qBy = py[qbase + 1], qBz = pz[qbase + 1];
  const float n2Ax = -2.f * qAx, n2Ay = -2.f * qAy, n2Az = -2.f * qAz;
  const float n2Bx = -2.f * qBx, n2By = -2.f * qBy, n2Bz = -2.f * qBz;
  const float qAsq = fmaf(qAx, qAx, fmaf(qAy, qAy, qAz * qAz));
  const float qBsq = fmaf(qBx, qBx, fmaf(qBy, qBy, qBz * qBz));
  const float nsx = grp ? n2Bx : n2Ax;            // self-query consts (seed)
  const float nsy = grp ? n2By : n2Ay;
  const float nsz = grp ? n2Bz : n2Az;
  const float sqs = grp ? qBsq : qAsq;
  const float qsx = grp ? qBx : qAx;
  const float qsy = grp ? qBy : qAy;
  const float qsz = grp ? qBz : qAz;
  const bool holder = (sub < 16);

  // ---- seed: Tv0 = exact 16th-smallest d2 of the 64-slot sorted window ----
  float Tv0A, Tv0B;
  {
    int rk = rank[base + q];                      // uniform within each half
    int seedW = rk & ~63;
    float4 c0 = spos[base + seedW + sub];
    float4 c1 = spos[base + seedW + 32 + sub];
    float sd = fmaf(c0.z, nsz, fmaf(c0.y, nsy, fmaf(c0.x, nsx, c0.w + sqs)));
    float se = fmaf(c1.z, nsz, fmaf(c1.y, nsy, fmaf(c1.x, nsx, c1.w + sqs)));
    BSORT32(sd)
    BSORT32(se)
    float ser = SWZF(se, 0x7C1F);                 // reverse within 32 lanes
    sd = fminf(sd, ser);                          // bitonic lower-32 of union
    BCLEAN32(sd)
    Tv0A = RDLANEF(sd, 15);
    Tv0B = RDLANEF(sd, 47);
  }
  float TvA = Tv0A, TvB = Tv0B;
  float bd = 3.4e38f;                             // holders: sorted top-16 d2
  int bi = 0;                                     // original candidate index

  for (int ch = 0; ch < 4; ++ch) {
    __syncthreads();
    for (int i = threadIdx.x; i < 2048; i += 512) {
      int j = (ch << 11) + i;
      float x = px[j], y = py[j], z = pz[j];
      cpos[i] = make_float4(x, y, z, fmaf(x, x, fmaf(y, y, z * z)));
    }
    __syncthreads();
    for (int t = 0; t < 32; ++t) {
      float4 cp = cpos[(t << 6) + lane];
      float d2A = fmaf(cp.z, n2Az, fmaf(cp.y, n2Ay, fmaf(cp.x, n2Ax, cp.w + qAsq)));
      float d2B = fmaf(cp.z, n2Bz, fmaf(cp.y, n2By, fmaf(cp.x, n2Bx, cp.w + qBsq)));
      unsigned long long mA = __ballot(d2A <= TvA);
      unsigned long long mB = __ballot(d2B <= TvB);
      if (mA | mB) {
        const int cb = (ch << 11) + (t << 6);
        while (mA) {
          int l = __builtin_ctzll(mA);
          mA &= mA - 1;
          float v = RDLANEF(d2A, l);
          if (v > TvA) continue;                  // stale vs tightened T
          int vi = cb + l;
          float ud = DPPF(bd);                    // prev-lane value (in-row)
          int ui = DPPI(bi);
          bool gt = (lane < 16) && (bd > v);
          bool first = (sub == 0) || (ud <= v);
          if (gt) {
            bd = first ? v : ud;
            bi = first ? vi : ui;
          }
          TvA = fminf(Tv0A, RDLANEF(bd, 15));
        }
        while (mB) {
          int l = __builtin_ctzll(mB);
          mB &= mB - 1;
          float v = RDLANEF(d2B, l);
          if (v > TvB) continue;
          int vi = cb + l;
          float ud = DPPF(bd);
          int ui = DPPI(bi);
          bool gt = (lane >= 32) && (lane < 48) && (bd > v);
          bool first = (sub == 0) || (ud <= v);
          if (gt) {
            bd = first ? v : ud;
            bi = first ? vi : ui;
          }
          TvB = fminf(Tv0B, RDLANEF(bd, 47));
        }
      }
    }
  }

  // exact-diff distance (matches reference) + softmax over each 16
  float dx = qsx - px[bi], dy = qsy - py[bi], dz = qsz - pz[bi];
  float dd = fmaxf(sqrtf(fmaf(dx, dx, fmaf(dy, dy, dz * dz))), 1e-6f);
  float logit = -dd * 5.0f;                       // 1/TAU = 5
  float mx = holder ? logit : -3.4e38f;
  mx = fmaxf(mx, SWZF(mx, 0x041F));
  mx = fmaxf(mx, SWZF(mx, 0x081F));
  mx = fmaxf(mx, SWZF(mx, 0x101F));
  mx = fmaxf(mx, SWZF(mx, 0x201F));
  float e = holder ? __expf(logit - mx) : 0.f;
  float s = e;
  s += SWZF(s, 0x041F);
  s += SWZF(s, 0x081F);
  s += SWZF(s, 0x101F);
  s += SWZF(s, 0x201F);
  if (holder) {
    size_t o = ((size_t)b * NPTS + q) * KNN + sub;
    nn_idx[o] = bi;
    nn_w[o] = e / s;
  }
}

// ------- K2: FUSED agg + GEMM1: h = [xT | agg][32x256] x w1^T + BN1 stats ---
// Inner product via packed f32x2 accumulation -> v_pk_fma_f32 (2 FMA/instr).
#define GEMM_CHUNK(ASRC)                                                     \
    _Pragma("unroll")                                                        \
    for (int cq = 0; cq < 16; ++cq) {                                        \
      int c = cq << 2;                                                       \
      float4 a[4], w[4];                                                     \
      _Pragma("unroll")                                                      \
      for (int i = 0; i < 4; ++i) a[i] = ASRC;                               \
      _Pragma("unroll")                                                      \
      for (int j = 0; j < 4; ++j) w[j] = *(const float4*)&wlds[og + (j << 5)][c]; \
      _Pragma("unroll")                                                      \
      for (int i = 0; i < 4; ++i) {                                          \
        f32x2 a01 = {a[i].x, a[i].y}, a23 = {a[i].z, a[i].w};                \
        _Pragma("unroll")                                                    \
        for (int j = 0; j < 4; ++j) {                                        \
          f32x2 w01 = {w[j].x, w[j].y}, w23 = {w[j].z, w[j].w};              \
          acc2[i][j] += a01 * w01;                                           \
          acc2[i][j] += a23 * w23;                                           \
        }                                                                    \
      }                                                                      \
    }

__global__ __launch_bounds__(256) void k_gemm1(const float* __restrict__ xT,
                                               const int* __restrict__ nn_idx,
                                               const float* __restrict__ nn_w,
                                               const float* __restrict__ w1,
                                               float* __restrict__ h_pre,
                                               float* __restrict__ stats1) {
  __shared__ float alds[32][68];
  __shared__ float wlds[128][68];
  __shared__ float aggl[32][132];
  __shared__ float sred[256];
  int b = blockIdx.x >> 8;
  int r0 = (blockIdx.x & 255) << 5;
  const float* xTb = xT + (size_t)b * NPTS * CCH;
  int rg = threadIdx.x & 7, og = threadIdx.x >> 3;
  f32x2 acc2[4][4];
#pragma unroll
  for (int i = 0; i < 4; ++i)
#pragma unroll
    for (int j = 0; j < 4; ++j) acc2[i][j] = (f32x2){0.f, 0.f};
  sred[threadIdx.x] = 0.f;

  {  // aggregation prologue: thread = (row r = tid>>3, 16-ch group cg = tid&7)
    int r = threadIdx.x >> 3, cg = threadIdx.x & 7;
    size_t o = ((size_t)b * NPTS + r0 + r) * KNN;
    float ag[16];
#pragma unroll
    for (int i = 0; i < 16; ++i) ag[i] = 0.f;
    for (int k = 0; k < KNN; ++k) {
      int idx = nn_idx[o + k];
      float w = nn_w[o + k];
      const float4* src = (const float4*)(xTb + (size_t)idx * CCH + (cg << 4));
#pragma unroll
      for (int u = 0; u < 4; ++u) {
        float4 v = src[u];
        ag[u * 4 + 0] = fmaf(w, v.x, ag[u * 4 + 0]);
        ag[u * 4 + 1] = fmaf(w, v.y, ag[u * 4 + 1]);
        ag[u * 4 + 2] = fmaf(w, v.z, ag[u * 4 + 2]);
        ag[u * 4 + 3] = fmaf(w, v.w, ag[u * 4 + 3]);
      }
    }
#pragma unroll
    for (int u = 0; u < 4; ++u)
      *(float4*)&aggl[r][(cg << 4) + (u << 2)] =
          make_float4(ag[u * 4], ag[u * 4 + 1], ag[u * 4 + 2], ag[u * 4 + 3]);
  }

  for (int ch = 0; ch < 4; ++ch) {
    __syncthreads();   // ch=0 barrier also publishes aggl for ch>=2 reads
    if (ch < 2) {
#pragma unroll
      for (int it = 0; it < 2; ++it) {            // stage A (xT half): 32 x 64
        int i = threadIdx.x + it * 256;
        int r = i >> 4, kq = i & 15;
        *(float4*)&alds[r][kq << 2] =
            *(const float4*)(xTb + (size_t)(r0 + r) * CCH + (ch << 6) + (kq << 2));
      }
    }
#pragma unroll
    for (int it = 0; it < 8; ++it) {              // stage W: 128 x 64
      int i = threadIdx.x + it * 256;
      int h = i >> 4, kq = i & 15;
      *(float4*)&wlds[h][kq << 2] =
          *(const float4*)(w1 + (size_t)h * 256 + (ch << 6) + (kq << 2));
    }
    __syncthreads();
    if (ch < 2) {
      GEMM_CHUNK(*(const float4*)&alds[rg + (i << 3)][c])
    } else {
      GEMM_CHUNK(*(const float4*)&aggl[rg + (i << 3)][((ch - 2) << 6) + c])
    }
  }
  float acc[4][4];
#pragma unroll
  for (int i = 0; i < 4; ++i)
#pragma unroll
    for (int j = 0; j < 4; ++j) acc[i][j] = acc2[i][j].x + acc2[i][j].y;
#pragma unroll
  for (int i = 0; i < 4; ++i) {
    int row = r0 + rg + (i << 3);
    float* dst = h_pre + ((size_t)b * NPTS + row) * CCH;
#pragma unroll
    for (int j = 0; j < 4; ++j) dst[og + (j << 5)] = acc[i][j];
  }
#pragma unroll
  for (int j = 0; j < 4; ++j) {
    float ps = acc[0][j] + acc[1][j] + acc[2][j] + acc[3][j];
    float pq = acc[0][j] * acc[0][j] + acc[1][j] * acc[1][j] +
               acc[2][j] * acc[2][j] + acc[3][j] * acc[3][j];
    atomicAdd(&sred[og + (j << 5)], ps);
    atomicAdd(&sred[128 + og + (j << 5)], pq);
  }
  __syncthreads();
  atomicAdd(&stats1[threadIdx.x], sred[threadIdx.x]);
}

// ---------------- K4: BN1+ReLU + GEMM2 + BN2 stats ----------------
__global__ __launch_bounds__(256) void k_gemm2(const float* __restrict__ h_pre,
                                               const float* __restrict__ stats1,
                                               const float* __restrict__ g1,
                                               const float* __restrict__ b1,
                                               const float* __restrict__ w2,
                                               float* __restrict__ y_pre,
                                               float* __restrict__ stats2) {
  __shared__ float alds[32][68];
  __shared__ float wlds[128][68];
  __shared__ float sred[256];
  __shared__ float scs[128], shs[128];
  int b = blockIdx.x >> 8;
  int r0 = (blockIdx.x & 255) << 5;
  int rg = threadIdx.x & 7, og = threadIdx.x >> 3;
  f32x2 acc2[4][4];
#pragma unroll
  for (int i = 0; i < 4; ++i)
#pragma unroll
    for (int j = 0; j < 4; ++j) acc2[i][j] = (f32x2){0.f, 0.f};
  sred[threadIdx.x] = 0.f;
  if (threadIdx.x < 128) {
    int c = threadIdx.x;
    float sm = stats1[c] * (1.f / 16384.f);
    float sq = stats1[128 + c] * (1.f / 16384.f);
    float var = fmaxf(sq - sm * sm, 0.f);
    float sc = g1[c] * rsqrtf(var + 1e-5f);
    scs[c] = sc;
    shs[c] = b1[c] - sm * sc;
  }
  for (int ch = 0; ch < 2; ++ch) {
    __syncthreads();
#pragma unroll
    for (int it = 0; it < 2; ++it) {
      int i = threadIdx.x + it * 256;
      int r = i >> 4, kq = i & 15;
      int c = (ch << 6) + (kq << 2);
      float4 v = *(const float4*)(h_pre + ((size_t)b * NPTS + r0 + r) * CCH + c);
      float4 sc = *(const float4*)&scs[c];
      float4 sh = *(const float4*)&shs[c];
      v.x = fmaxf(fmaf(v.x, sc.x, sh.x), 0.f);
      v.y = fmaxf(fmaf(v.y, sc.y, sh.y), 0.f);
      v.z = fmaxf(fmaf(v.z, sc.z, sh.z), 0.f);
      v.w = fmaxf(fmaf(v.w, sc.w, sh.w), 0.f);
      *(float4*)&alds[r][kq << 2] = v;
    }
#pragma unroll
    for (int it = 0; it < 8; ++it) {
      int i = threadIdx.x + it * 256;
      int h = i >> 4, kq = i & 15;
      *(float4*)&wlds[h][kq << 2] =
          *(const float4*)(w2 + (size_t)h * CCH + (ch << 6) + (kq << 2));
    }
    __syncthreads();
#pragma unroll
    for (int cq = 0; cq < 16; ++cq) {
      int c = cq << 2;
      float4 a[4], w[4];
#pragma unroll
      for (int i = 0; i < 4; ++i) a[i] = *(const float4*)&alds[rg + (i << 3)][c];
#pragma unroll
      for (int j = 0; j < 4; ++j) w[j] = *(const float4*)&wlds[og + (j << 5)][c];
#pragma unroll
      for (int i = 0; i < 4; ++i) {
        f32x2 a01 = {a[i].x, a[i].y}, a23 = {a[i].z, a[i].w};
#pragma unroll
        for (int j = 0; j < 4; ++j) {
          f32x2 w01 = {w[j].x, w[j].y}, w23 = {w[j].z, w[j].w};
          acc2[i][j] += a01 * w01;
          acc2[i][j] += a23 * w23;
        }
      }
    }
  }
  float acc[4][4];
#pragma unroll
  for (int i = 0; i < 4; ++i)
#pragma unroll
    for (int j = 0; j < 4; ++j) acc[i][j] = acc2[i][j].x + acc2[i][j].y;
#pragma unroll
  for (int i = 0; i < 4; ++i) {
    int row = r0 + rg + (i << 3);
    float* dst = y_pre + ((size_t)b * NPTS + row) * CCH;
#pragma unroll
    for (int j = 0; j < 4; ++j) dst[og + (j << 5)] = acc[i][j];
  }
#pragma unroll
  for (int j = 0; j < 4; ++j) {
    float ps = acc[0][j] + acc[1][j] + acc[2][j] + acc[3][j];
    float pq = acc[0][j] * acc[0][j] + acc[1][j] * acc[1][j] +
               acc[2][j] * acc[2][j] + acc[3][j] * acc[3][j];
    atomicAdd(&sred[og + (j << 5)], ps);
    atomicAdd(&sred[128 + og + (j << 5)], pq);
  }
  __syncthreads();
  atomicAdd(&stats2[threadIdx.x], sred[threadIdx.x]);
}

// ---------------- K6: SE pool (256 blocks, 64 rows each) ----------------
__global__ __launch_bounds__(256) void k_sepool(const float* __restrict__ y_pre,
                                                const float* __restrict__ stats2,
                                                const float* __restrict__ g2,
                                                const float* __restrict__ b2,
                                                float* __restrict__ s_sum) {
  __shared__ float red[256];
  int b = blockIdx.x >> 7;
  int r0 = (blockIdx.x & 127) << 6;
  int c = threadIdx.x & 127, half = threadIdx.x >> 7;
  float sm = stats2[c] * (1.f / 16384.f);
  float sq = stats2[128 + c] * (1.f / 16384.f);
  float var = fmaxf(sq - sm * sm, 0.f);
  float sc = g2[c] * rsqrtf(var + 1e-5f);
  float sh = b2[c] - sm * sc;
  float acc = 0.f;
  for (int r = half; r < 64; r += 2) {
    float v = y_pre[((size_t)b * NPTS + r0 + r) * CCH + c];
    acc += fmaxf(v * sc + sh, 0.f);
  }
  red[threadIdx.x] = acc;
  __syncthreads();
  if (half == 0) atomicAdd(&s_sum[b * CCH + c], red[c] + red[128 + c]);
}

// ---------------- K7: SE gate ----------------
__global__ __launch_bounds__(128) void k_segate(const float* __restrict__ s_sum,
                                                const float* __restrict__ fc1w,
                                                const float* __restrict__ fc1b,
                                                const float* __restrict__ fc2w,
                                                const float* __restrict__ fc2b,
                                                float* __restrict__ gate) {
  __shared__ float s[128];
  __shared__ float hid[8];
  int b = blockIdx.x, t = threadIdx.x;
  s[t] = s_sum[b * CCH + t] * (1.f / 8192.f);
  __syncthreads();
  if (t < 8) {
    float a = fc1b[t];
    for (int c = 0; c < 128; ++c) a += s[c] * fc1w[t * 128 + c];
    hid[t] = fmaxf(a, 0.f);
  }
  __syncthreads();
  float a = fc2b[t];
#pragma unroll
  for (int j = 0; j < 8; ++j) a += hid[j] * fc2w[t * 8 + j];
  gate[b * CCH + t] = 1.f / (1.f + __expf(-a));
}

// ---------------- K8: bn2+relu+gate + residual + transpose ----------------
__global__ __launch_bounds__(256) void k_out(const float* __restrict__ x,
                                             const float* __restrict__ y_pre,
                                             const float* __restrict__ stats2,
                                             const float* __restrict__ g2,
                                             const float* __restrict__ b2,
                                             const float* __restrict__ gate,
                                             float* __restrict__ out) {
  __shared__ float t[64][129];
  int b = blockIdx.x >> 7;
  int n0 = (blockIdx.x & 127) << 6;
  {
    int c = threadIdx.x & 127;
    float sm = stats2[c] * (1.f / 16384.f);
    float sq = stats2[128 + c] * (1.f / 16384.f);
    float var = fmaxf(sq - sm * sm, 0.f);
    float sc = g2[c] * rsqrtf(var + 1e-5f);
    float sh = b2[c] - sm * sc;
    float gt = gate[b * CCH + c];
    for (int r = threadIdx.x >> 7; r < 64; r += 2) {
      float v = y_pre[((size_t)b * NPTS + n0 + r) * CCH + c];
      t[r][c] = fmaxf(v * sc + sh, 0.f) * gt;
    }
  }
  __syncthreads();
  int nl = threadIdx.x & 63, cg = threadIdx.x >> 6;
  for (int cc = cg; cc < CCH; cc += 4) {
    size_t o = ((size_t)b * CCH + cc) * NPTS + n0 + nl;
    out[o] = x[o] + t[nl][cc];
  }
}

extern "C" void kernel_launch(void* const* d_in, const int* in_sizes, int n_in,
                              void* d_out, int out_size, void* d_ws, size_t ws_size,
                              hipStream_t stream) {
  const float* x = (const float*)d_in[0];
  const float* pos = (const float*)d_in[1];
  const float* w1 = (const float*)d_in[2];
  const float* g1 = (const float*)d_in[3];
  const float* b1 = (const float*)d_in[4];
  const float* w2 = (const float*)d_in[5];
  const float* g2 = (const float*)d_in[6];
  const float* b2 = (const float*)d_in[7];
  const float* fc1w = (const float*)d_in[8];
  const float* fc1b = (const float*)d_in[9];
  const float* fc2w = (const float*)d_in[10];
  const float* fc2b = (const float*)d_in[11];
  float* out = (float*)d_out;
  char* ws = (char*)d_ws;
  const size_t MB = 1048576;

  float* xT = (float*)(ws + 0);             //  8 MB [B,N,128]
  int* nn_idx = (int*)(ws + 8 * MB);        //  1 MB
  float* nn_w = (float*)(ws + 9 * MB);      //  1 MB
  float* h_pre = (float*)(ws + 18 * MB);    //  8 MB
  // meta at 26MB: [stats 4KB (zeroed)][hist 32KB (zeroed)][hoff 32KB]
  //               [spos 256KB][rank 64KB]
  char* meta = ws + 26 * MB;
  float* stats = (float*)meta;
  int* hist = (int*)(meta + 4096);
  int* hoff = (int*)(meta + 4096 + 32768);
  float4* spos = (float4*)(meta + 4096 + 65536);
  int* rank = (int*)(meta + 4096 + 65536 + 262144);
  float* y_pre;
  if (ws_size >= 35 * MB) {
    y_pre = (float*)(ws + 27 * MB);         //  8 MB disjoint
  } else {
    y_pre = (float*)(ws + 0);               //  aliases xT (dead after k_gemm1,
  }                                         //  rewritten first thing next call)
  float* stats1 = stats;
  float* stats2 = stats + 256;
  float* s_sum = stats + 512;
  float* gate = stats + 768;

  k_zero<<<36, 256, 0, stream>>>(stats);    // stats (4KB) + hist (32KB)
  k_hist<<<64, 256, 0, stream>>>(pos, hist);
  k_scan<<<1, 1024, 0, stream>>>(hist, hoff);
  k_scatter<<<64, 256, 0, stream>>>(pos, hoff, spos, rank);
  k_transpose<<<1024, 256, 0, stream>>>(x, xT);
  k_knn<<<1024, 512, 0, stream>>>(pos, spos, rank, nn_idx, nn_w);
  k_gemm1<<<512, 256, 0, stream>>>(xT, nn_idx, nn_w, w1, h_pre, stats1);
  k_gemm2<<<512, 256, 0, stream>>>(h_pre, stats1, g1, b1, w2, y_pre, stats2);
  k_sepool<<<256, 256, 0, stream>>>(y_pre, stats2, g2, b2, s_sum);
  k_segate<<<2, 128, 0, stream>>>(s_sum, fc1w, fc1b, fc2w, fc2b, gate);
  k_out<<<256, 256, 0, stream>>>(x, y_pre, stats2, g2, b2, gate, out);
}